// Round 6
// baseline (31.571 us; speedup 1.0000x reference)
//
#include <hip/hip_runtime.h>
#include <hip/hip_fp16.h>

#define DX 160
#define DY 192
#define DZ 160
#define PLANE (DY*DZ)
#define NVOX (DX*DY*DZ)

#define YC   8             // interior y rows per block
#define NYB  (DY/YC)       // 24
#define XC   16            // interior x slices per block
#define NXB  (DX/XC)       // 10
#define NS   (XC+4)        // 20 slices per block
#define ROWS (YC+4)        // 12 slab rows
#define ZP   80            // z-pairs (z = 2*zp, 2*zp+1)
#define NT   (YC*ZP)       // 640 threads = 10 waves
#define RAWSLOTS (ROWS*DZ) // 1920 float2 slots = exactly 3*NT

__device__ __forceinline__ int iclamp(int v, int hi) {
    return v < 0 ? 0 : (v > hi ? hi : v);
}

__device__ __forceinline__ __half2 h2(int v) {
    return __builtin_bit_cast(__half2, v);
}

// ---------------------------------------------------------------------------
// Fully fused LCC, single-barrier pipelined slice loop.
// grid = (NXB, NYB) = 240 blocks, block = 640 = (8 y, 80 zp).
// Pipeline (1 barrier/slice, depth-2 prefetch):
//   iter i: S2(i) from ybuf[i&1]; S1(i+1) rawS[(i+1)&1] -> ybuf[(i+1)&1];
//           W(i+2): regs -> rawS[i&1] (loads issued at iter i-1, ~1 full
//           iteration in flight so vmcnt wait is ~free); issue R(i+3);
//           __syncthreads().
// Every cross-thread buffer reuse is separated by >=1 barrier (parity math
// in comments below). Two named register sets A/B keep indexing static.
// ---------------------------------------------------------------------------
__global__ __launch_bounds__(NT, 2) void lcc_fused(const float* __restrict__ F,
                                                   const float* __restrict__ M,
                                                   float* __restrict__ partials) {
    __shared__ float4   rawS[2][ROWS * ZP];  // 2 x 15360 B
    __shared__ int4     ybA[2][YC * ZP];     // 2 x 10240 B
    __shared__ unsigned ybB[2][YC * ZP];     // 2 x  2560 B
    __shared__ float    red[1024];           //      4096 B  (total ~59.5 KB)

    const int tid = threadIdx.x;
    const int zp  = tid % ZP;
    const int ty  = tid / ZP;
    const int y0  = blockIdx.y * YC;
    const int x0  = blockIdx.x * XC;

    // hoisted staging offsets (3 float2 slots per thread, exact cover)
    int soff[3];
    #pragma unroll
    for (int k = 0; k < 3; ++k) {
        const int e   = tid + k * NT;
        const int row = e / DZ, zz = e % DZ;
        soff[k] = iclamp(y0 + row - 2, DY - 1) * DZ + zz;
    }

    // ---- pipeline helpers ----
    auto issueR = [&](int j, float (&pf)[3], float (&pm)[3]) {
        const int xx = iclamp(x0 + j - 2, DX - 1);
        const float* fp = F + (size_t)xx * PLANE;
        const float* mp = M + (size_t)xx * PLANE;
        #pragma unroll
        for (int k = 0; k < 3; ++k) { pf[k] = fp[soff[k]]; pm[k] = mp[soff[k]]; }
    };
    auto writeW = [&](int buf, const float (&pf)[3], const float (&pm)[3]) {
        #pragma unroll
        for (int k = 0; k < 3; ++k)
            ((float2*)rawS[buf])[tid + k * NT] = make_float2(pf[k], pm[k]);
    };
    auto stage1 = [&](int buf) {   // reads rawS[buf], writes ybuf[buf]
        float yA[5] = {0,0,0,0,0};
        float yB[5] = {0,0,0,0,0};
        #pragma unroll
        for (int k = 0; k < 5; ++k) {
            const float4 t = rawS[buf][(ty + k) * ZP + zp];
            yA[0] += t.x; yA[1] += t.y;
            yA[2] = fmaf(t.x, t.y, yA[2]);
            yA[3] = fmaf(t.x, t.x, yA[3]);
            yA[4] = fmaf(t.y, t.y, yA[4]);
            yB[0] += t.z; yB[1] += t.w;
            yB[2] = fmaf(t.z, t.w, yB[2]);
            yB[3] = fmaf(t.z, t.z, yB[3]);
            yB[4] = fmaf(t.w, t.w, yB[4]);
        }
        int4 w;
        w.x = __builtin_bit_cast(int, __floats2half2_rn(yA[0], yA[1]));
        w.y = __builtin_bit_cast(int, __floats2half2_rn(yA[2], yA[3]));
        w.z = __builtin_bit_cast(int, __floats2half2_rn(yB[0], yB[1]));
        w.w = __builtin_bit_cast(int, __floats2half2_rn(yB[2], yB[3]));
        ybA[buf][ty * ZP + zp] = w;
        ybB[buf][ty * ZP + zp] = __builtin_bit_cast(unsigned, __floats2half2_rn(yA[4], yB[4]));
    };

    // ---- x-window state ----
    float acc = 0.f;
    float sA[5], sB[5];
    unsigned hp[4][5];          // history: half2(SA[q], SB[q]) per step
    #pragma unroll
    for (int q = 0; q < 5; ++q) { sA[q] = 0.f; sB[q] = 0.f; }
    #pragma unroll
    for (int k = 0; k < 4; ++k)
        #pragma unroll
        for (int q = 0; q < 5; ++q) hp[k][q] = 0u;

    auto body = [&](int i, float (&pfW)[3], float (&pmW)[3],
                           float (&pfR)[3], float (&pmR)[3]) {
        const int par = i & 1;
        // ---- stage2: z-box from ybuf[par] (published by previous barrier) ----
        const int base = ty * ZP;
        int4 p0 = ybA[par][base + (zp == 0      ? 0      : zp - 1)];
        int4 p1 = ybA[par][base + zp];
        int4 p2 = ybA[par][base + (zp == ZP - 1 ? ZP - 1 : zp + 1)];
        unsigned b0 = ybB[par][base + (zp == 0      ? 0      : zp - 1)];
        unsigned b2 = ybB[par][base + (zp == ZP - 1 ? ZP - 1 : zp + 1)];
        const unsigned b1 = ybB[par][base + zp];
        if (zp == 0)      { p0.z = p0.x; p0.w = p0.y; b0 = (b0 & 0xffffu) | (b0 << 16); }
        if (zp == ZP - 1) { p2.x = p2.z; p2.y = p2.w; b2 = (b2 >> 16) | (b2 & 0xffff0000u); }

        const __half2 t0  = __hadd2(__hadd2(h2(p0.z), h2(p1.x)), __hadd2(h2(p1.z), h2(p2.x)));
        const __half2 A01 = __hadd2(t0, h2(p0.x));
        const __half2 B01 = __hadd2(t0, h2(p2.z));
        const __half2 t1  = __hadd2(__hadd2(h2(p0.w), h2(p1.y)), __hadd2(h2(p1.w), h2(p2.y)));
        const __half2 A23 = __hadd2(t1, h2(p0.y));
        const __half2 B23 = __hadd2(t1, h2(p2.w));
        const __half2 c0 = h2((int)b0), c1 = h2((int)b1), c2 = h2((int)b2);
        const float tb = __high2float(c0) + __low2float(c1) + __high2float(c1) + __low2float(c2);
        const float SA[5] = { __low2float(A01), __high2float(A01),
                              __low2float(A23), __high2float(A23),
                              tb + __low2float(c0) };
        const float SB[5] = { __low2float(B01), __high2float(B01),
                              __low2float(B23), __high2float(B23),
                              tb + __high2float(c2) };

        // ---- x running window + LCC ----
        #pragma unroll
        for (int q = 0; q < 5; ++q) { sA[q] += SA[q]; sB[q] += SB[q]; }
        if (i >= 4) {
            const float inv = 1.0f / 125.0f;
            {
                const float cross = sA[2] - sA[0] * sA[1] * inv;
                const float fvar  = sA[3] - sA[0] * sA[0] * inv;
                const float mvar  = sA[4] - sA[1] * sA[1] * inv;
                acc += cross * cross / (fvar * mvar + 0.1f);
            }
            {
                const float cross = sB[2] - sB[0] * sB[1] * inv;
                const float fvar  = sB[3] - sB[0] * sB[0] * inv;
                const float mvar  = sB[4] - sB[1] * sB[1] * inv;
                acc += cross * cross / (fvar * mvar + 0.1f);
            }
            #pragma unroll
            for (int q = 0; q < 5; ++q) {
                const __half2 v = h2((int)hp[0][q]);
                sA[q] -= __low2float(v);
                sB[q] -= __high2float(v);
            }
        }
        #pragma unroll
        for (int k = 0; k < 3; ++k)
            #pragma unroll
            for (int q = 0; q < 5; ++q) hp[k][q] = hp[k + 1][q];
        #pragma unroll
        for (int q = 0; q < 5; ++q)
            hp[3][q] = __builtin_bit_cast(unsigned, __floats2half2_rn(SA[q], SB[q]));

        // ---- S1(i+1): rawS[1-par] -> ybuf[1-par] (read pub'd last barrier) ----
        if (i + 1 < NS) stage1(1 - par);
        // ---- W(i+2): regs (issued iter i-1) -> rawS[par]; S1(i) readers of
        //      rawS[par] all passed the previous barrier ----
        if (i + 2 < NS) writeW(par, pfW, pmW);
        // ---- R(i+3): issue next loads; consumed by W at iter i+1 ----
        if (i + 3 < NS) issueR(i + 3, pfR, pmR);
        if (i + 1 < NS) __syncthreads();
    };

    // ---- prologue: fill pipeline ----
    float pfA[3], pmA[3], pfB[3], pmB[3];
    issueR(0, pfA, pmA);
    writeW(0, pfA, pmA);          // W(0) -> rawS[0]
    issueR(1, pfB, pmB);          // R(1) in flight
    __syncthreads();              // rawS[0] visible
    stage1(0);                    // S1(0) -> ybuf[0]
    writeW(1, pfB, pmB);          // W(1) -> rawS[1]
    issueR(2, pfA, pmA);          // R(2) -> regsA (consumed at iter 0)
    __syncthreads();              // ybuf[0], rawS[1] visible

    // ---- main loop: regs parity  W(i+2) uses regs[i&1], R(i+3) fills regs[(i+1)&1] ----
    #pragma unroll
    for (int ib = 0; ib < NS; ib += 2) {
        body(ib,     pfA, pmA, pfB, pmB);
        body(ib + 1, pfB, pmB, pfA, pmA);
    }

    // ---- block reduction (deterministic tree over 1024 padded slots) ----
    red[tid] = acc;
    if (tid < 1024 - NT) red[NT + tid] = 0.f;
    __syncthreads();
    #pragma unroll
    for (int st = 512; st > 0; st >>= 1) {
        if (tid < st) red[tid] += red[tid + st];
        __syncthreads();
    }
    if (tid == 0) partials[blockIdx.y * NXB + blockIdx.x] = red[0];
}

// ---------------------------------------------------------------------------
// Final deterministic reduction, writes -sum.
// ---------------------------------------------------------------------------
__global__ __launch_bounds__(256) void lcc_finalize(const float* __restrict__ partials,
                                                    int n, float* __restrict__ out) {
    __shared__ float red[256];
    float a = 0.f;
    for (int i = threadIdx.x; i < n; i += 256) a += partials[i];
    red[threadIdx.x] = a;
    __syncthreads();
    #pragma unroll
    for (int st = 128; st > 0; st >>= 1) {
        if (threadIdx.x < st) red[threadIdx.x] += red[threadIdx.x + st];
        __syncthreads();
    }
    if (threadIdx.x == 0) out[0] = -red[0];
}

// ---------------------------------------------------------------------------
// Fallback: direct 125-tap (only if ws is tiny).
// ---------------------------------------------------------------------------
__global__ __launch_bounds__(256) void lcc_direct(const float* __restrict__ f,
                                                  const float* __restrict__ m,
                                                  float* __restrict__ partials) {
    float acc = 0.f;
    for (int idx = blockIdx.x * 256 + threadIdx.x; idx < NVOX; idx += 256 * gridDim.x) {
        const int z = idx % DZ;
        const int y = (idx / DZ) % DY;
        const int x = idx / PLANE;
        float sf = 0, sm = 0, sfm = 0, sff = 0, smm = 0;
        for (int dx = -2; dx <= 2; ++dx) {
            const int xx = iclamp(x + dx, DX - 1);
            for (int dy = -2; dy <= 2; ++dy) {
                const int yy = iclamp(y + dy, DY - 1);
                const size_t b = (size_t)xx * PLANE + (size_t)yy * DZ;
                #pragma unroll
                for (int dz = -2; dz <= 2; ++dz) {
                    const int zz = iclamp(z + dz, DZ - 1);
                    const float fv = f[b + zz], mv = m[b + zz];
                    sf += fv; sm += mv; sfm += fv * mv; sff += fv * fv; smm += mv * mv;
                }
            }
        }
        const float inv = 1.0f / 125.0f;
        const float cross = sfm - sf * sm * inv;
        const float fvar  = sff - sf * sf * inv;
        const float mvar  = smm - sm * sm * inv;
        acc += cross * cross / (fvar * mvar + 0.1f);
    }
    __shared__ float red[256];
    red[threadIdx.x] = acc;
    __syncthreads();
    #pragma unroll
    for (int st = 128; st > 0; st >>= 1) {
        if (threadIdx.x < st) red[threadIdx.x] += red[threadIdx.x + st];
        __syncthreads();
    }
    if (threadIdx.x == 0) partials[blockIdx.x] = red[0];
}

extern "C" void kernel_launch(void* const* d_in, const int* in_sizes, int n_in,
                              void* d_out, int out_size, void* d_ws, size_t ws_size,
                              hipStream_t stream) {
    const float* f = (const float*)d_in[0];
    const float* m = (const float*)d_in[1];
    float* out = (float*)d_out;

    if (ws_size >= 4096) {
        float* partials = (float*)d_ws;
        lcc_fused<<<dim3(NXB, NYB), NT, 0, stream>>>(f, m, partials);
        lcc_finalize<<<1, 256, 0, stream>>>(partials, NXB * NYB, out);
    } else {
        const int nb = 512;
        float* partials = (float*)d_ws;
        lcc_direct<<<nb, 256, 0, stream>>>(f, m, partials);
        lcc_finalize<<<1, 256, 0, stream>>>(partials, nb, out);
    }
}

// Round 7
// 30.050 us; speedup vs baseline: 1.0506x; 1.0506x over previous
//
#include <hip/hip_runtime.h>
#include <hip/hip_fp16.h>

#define DX 160
#define DY 192
#define DZ 160
#define PLANE (DY*DZ)
#define NVOX (DX*DY*DZ)

#define YC   8             // interior y rows per block
#define NYB  (DY/YC)       // 24
#define XC   8             // interior x slices per block (R7: 16->8 for 2 blocks/CU)
#define NXB  (DX/XC)       // 20
#define NS   (XC+4)        // 12 slices per block
#define ROWS (YC+4)        // 12 slab rows
#define ZP   80            // z-pairs (z = 2*zp, 2*zp+1)
#define NT   (YC*ZP)       // 640 threads = 10 waves
#define RAWSLOTS (ROWS*DZ) // 1920 float2 slots = exactly 3*NT

__device__ __forceinline__ int iclamp(int v, int hi) {
    return v < 0 ? 0 : (v > hi ? hi : v);
}

__device__ __forceinline__ __half2 h2(int v) {
    return __builtin_bit_cast(__half2, v);
}

// ---------------------------------------------------------------------------
// Fully fused LCC (R5 structure: single-buffered LDS, 2 barriers/slice,
// register prefetch of slice i+1). R7 change: XC=8 -> grid (20,24)=480 blocks
// = 2 blocks/CU = 20 waves/CU. R6's 1-barrier pipeline was neutral; the
// counters showed latency-bound at 24% occupancy (grid 240 < 256 CUs), so
// the lever is resident-wave count, not barrier count. LDS 32 KB -> 2
// blocks/CU fit easily.
// ---------------------------------------------------------------------------
__global__ __launch_bounds__(NT, 2) void lcc_fused(const float* __restrict__ F,
                                                   const float* __restrict__ M,
                                                   float* __restrict__ partials) {
    __shared__ float4   rawS[ROWS * ZP];  // (f(z0),m(z0),f(z1),m(z1)) : 15360 B
    __shared__ int4     ybA[YC * ZP];     // half2(q0,q1)|half2(q2,q3) : 10240 B
    __shared__ unsigned ybB[YC * ZP];     // half2(q4_z0, q4_z1) :  2560 B
    __shared__ float    red[1024];        //  4096 B   (total ~32.3 KB)

    const int tid = threadIdx.x;
    const int zp  = tid % ZP;
    const int ty  = tid / ZP;
    const int y0  = blockIdx.y * YC;
    const int x0  = blockIdx.x * XC;

    // hoisted staging offsets (3 float2 slots per thread, exact cover)
    int soff[3];
    #pragma unroll
    for (int k = 0; k < 3; ++k) {
        const int e   = tid + k * NT;
        const int row = e / DZ, zz = e % DZ;
        soff[k] = iclamp(y0 + row - 2, DY - 1) * DZ + zz;
    }

    // ---- stage slice 0 ----
    {
        const int xx = iclamp(x0 - 2, DX - 1);
        const float* fp = F + (size_t)xx * PLANE;
        const float* mp = M + (size_t)xx * PLANE;
        #pragma unroll
        for (int k = 0; k < 3; ++k)
            ((float2*)rawS)[tid + k * NT] = make_float2(fp[soff[k]], mp[soff[k]]);
    }
    __syncthreads();

    float acc = 0.f;
    float sA[5], sB[5];
    unsigned hp[4][5];          // history: half2(SA[q], SB[q]) per step
    #pragma unroll
    for (int q = 0; q < 5; ++q) { sA[q] = 0.f; sB[q] = 0.f; }
    #pragma unroll
    for (int k = 0; k < 4; ++k)
        #pragma unroll
        for (int q = 0; q < 5; ++q) hp[k][q] = 0u;

    for (int i = 0; i < NS; ++i) {
        // ---- stage1: y-box (5 row taps) in f32 registers ----
        float yA[5] = {0,0,0,0,0};  // q: f, m, fm, ff, mm  @ z0
        float yB[5] = {0,0,0,0,0};  //                      @ z1
        #pragma unroll
        for (int k = 0; k < 5; ++k) {
            const float4 t = rawS[(ty + k) * ZP + zp];
            yA[0] += t.x; yA[1] += t.y;
            yA[2] = fmaf(t.x, t.y, yA[2]);
            yA[3] = fmaf(t.x, t.x, yA[3]);
            yA[4] = fmaf(t.y, t.y, yA[4]);
            yB[0] += t.z; yB[1] += t.w;
            yB[2] = fmaf(t.z, t.w, yB[2]);
            yB[3] = fmaf(t.z, t.z, yB[3]);
            yB[4] = fmaf(t.w, t.w, yB[4]);
        }
        // ---- pack Y -> fp16 ybuf ----
        int4 w;
        w.x = __builtin_bit_cast(int, __floats2half2_rn(yA[0], yA[1]));
        w.y = __builtin_bit_cast(int, __floats2half2_rn(yA[2], yA[3]));
        w.z = __builtin_bit_cast(int, __floats2half2_rn(yB[0], yB[1]));
        w.w = __builtin_bit_cast(int, __floats2half2_rn(yB[2], yB[3]));
        ybA[ty * ZP + zp] = w;
        ybB[ty * ZP + zp] = __builtin_bit_cast(unsigned, __floats2half2_rn(yA[4], yB[4]));

        // ---- prefetch slice i+1 into regs (latency hides under stage2) ----
        float pf[3], pm[3];
        if (i + 1 < NS) {
            const int xx = iclamp(x0 + (i + 1) - 2, DX - 1);
            const float* fp = F + (size_t)xx * PLANE;
            const float* mp = M + (size_t)xx * PLANE;
            #pragma unroll
            for (int k = 0; k < 3; ++k) { pf[k] = fp[soff[k]]; pm[k] = mp[soff[k]]; }
        }

        __syncthreads();   // ybuf visible; all rawS reads of slice i done

        // ---- stage2: z-box over pairs (taps z0-2 .. z0+3) ----
        const int base = ty * ZP;
        int4 p0 = ybA[base + (zp == 0      ? 0      : zp - 1)];
        int4 p1 = ybA[base + zp];
        int4 p2 = ybA[base + (zp == ZP - 1 ? ZP - 1 : zp + 1)];
        unsigned b0 = ybB[base + (zp == 0      ? 0      : zp - 1)];
        unsigned b2 = ybB[base + (zp == ZP - 1 ? ZP - 1 : zp + 1)];
        const unsigned b1 = ybB[base + zp];
        if (zp == 0)      { p0.z = p0.x; p0.w = p0.y; b0 = (b0 & 0xffffu) | (b0 << 16); }
        if (zp == ZP - 1) { p2.x = p2.z; p2.y = p2.w; b2 = (b2 >> 16) | (b2 & 0xffff0000u); }

        // packed 5-tap sums: T = common 4 taps; Sz0 = T + low tap; Sz1 = T + high tap
        const __half2 t0  = __hadd2(__hadd2(h2(p0.z), h2(p1.x)), __hadd2(h2(p1.z), h2(p2.x)));
        const __half2 A01 = __hadd2(t0, h2(p0.x));
        const __half2 B01 = __hadd2(t0, h2(p2.z));
        const __half2 t1  = __hadd2(__hadd2(h2(p0.w), h2(p1.y)), __hadd2(h2(p1.w), h2(p2.y)));
        const __half2 A23 = __hadd2(t1, h2(p0.y));
        const __half2 B23 = __hadd2(t1, h2(p2.w));
        const __half2 c0 = h2((int)b0), c1 = h2((int)b1), c2 = h2((int)b2);
        const float tb = __high2float(c0) + __low2float(c1) + __high2float(c1) + __low2float(c2);
        const float SA[5] = { __low2float(A01), __high2float(A01),
                              __low2float(A23), __high2float(A23),
                              tb + __low2float(c0) };
        const float SB[5] = { __low2float(B01), __high2float(B01),
                              __low2float(B23), __high2float(B23),
                              tb + __high2float(c2) };

        // ---- x running window + LCC ----
        #pragma unroll
        for (int q = 0; q < 5; ++q) { sA[q] += SA[q]; sB[q] += SB[q]; }
        if (i >= 4) {
            const float inv = 1.0f / 125.0f;
            {
                const float cross = sA[2] - sA[0] * sA[1] * inv;
                const float fvar  = sA[3] - sA[0] * sA[0] * inv;
                const float mvar  = sA[4] - sA[1] * sA[1] * inv;
                acc += cross * cross / (fvar * mvar + 0.1f);
            }
            {
                const float cross = sB[2] - sB[0] * sB[1] * inv;
                const float fvar  = sB[3] - sB[0] * sB[0] * inv;
                const float mvar  = sB[4] - sB[1] * sB[1] * inv;
                acc += cross * cross / (fvar * mvar + 0.1f);
            }
            #pragma unroll
            for (int q = 0; q < 5; ++q) {
                const __half2 v = h2((int)hp[0][q]);
                sA[q] -= __low2float(v);
                sB[q] -= __high2float(v);
            }
        }
        #pragma unroll
        for (int k = 0; k < 3; ++k)
            #pragma unroll
            for (int q = 0; q < 5; ++q) hp[k][q] = hp[k + 1][q];
        #pragma unroll
        for (int q = 0; q < 5; ++q)
            hp[3][q] = __builtin_bit_cast(unsigned, __floats2half2_rn(SA[q], SB[q]));

        // ---- write prefetched slice i+1 into rawS ----
        if (i + 1 < NS) {
            #pragma unroll
            for (int k = 0; k < 3; ++k)
                ((float2*)rawS)[tid + k * NT] = make_float2(pf[k], pm[k]);
            __syncthreads();   // rawS ready; ybuf reads done
        }
    }

    // ---- block reduction (deterministic tree over 1024 padded slots) ----
    red[tid] = acc;
    if (tid < 1024 - NT) red[NT + tid] = 0.f;
    __syncthreads();
    #pragma unroll
    for (int st = 512; st > 0; st >>= 1) {
        if (tid < st) red[tid] += red[tid + st];
        __syncthreads();
    }
    if (tid == 0) partials[blockIdx.y * NXB + blockIdx.x] = red[0];
}

// ---------------------------------------------------------------------------
// Final deterministic reduction, writes -sum.
// ---------------------------------------------------------------------------
__global__ __launch_bounds__(256) void lcc_finalize(const float* __restrict__ partials,
                                                    int n, float* __restrict__ out) {
    __shared__ float red[256];
    float a = 0.f;
    for (int i = threadIdx.x; i < n; i += 256) a += partials[i];
    red[threadIdx.x] = a;
    __syncthreads();
    #pragma unroll
    for (int st = 128; st > 0; st >>= 1) {
        if (threadIdx.x < st) red[threadIdx.x] += red[threadIdx.x + st];
        __syncthreads();
    }
    if (threadIdx.x == 0) out[0] = -red[0];
}

// ---------------------------------------------------------------------------
// Fallback: direct 125-tap (only if ws is tiny).
// ---------------------------------------------------------------------------
__global__ __launch_bounds__(256) void lcc_direct(const float* __restrict__ f,
                                                  const float* __restrict__ m,
                                                  float* __restrict__ partials) {
    float acc = 0.f;
    for (int idx = blockIdx.x * 256 + threadIdx.x; idx < NVOX; idx += 256 * gridDim.x) {
        const int z = idx % DZ;
        const int y = (idx / DZ) % DY;
        const int x = idx / PLANE;
        float sf = 0, sm = 0, sfm = 0, sff = 0, smm = 0;
        for (int dx = -2; dx <= 2; ++dx) {
            const int xx = iclamp(x + dx, DX - 1);
            for (int dy = -2; dy <= 2; ++dy) {
                const int yy = iclamp(y + dy, DY - 1);
                const size_t b = (size_t)xx * PLANE + (size_t)yy * DZ;
                #pragma unroll
                for (int dz = -2; dz <= 2; ++dz) {
                    const int zz = iclamp(z + dz, DZ - 1);
                    const float fv = f[b + zz], mv = m[b + zz];
                    sf += fv; sm += mv; sfm += fv * mv; sff += fv * fv; smm += mv * mv;
                }
            }
        }
        const float inv = 1.0f / 125.0f;
        const float cross = sfm - sf * sm * inv;
        const float fvar  = sff - sf * sf * inv;
        const float mvar  = smm - sm * sm * inv;
        acc += cross * cross / (fvar * mvar + 0.1f);
    }
    __shared__ float red[256];
    red[threadIdx.x] = acc;
    __syncthreads();
    #pragma unroll
    for (int st = 128; st > 0; st >>= 1) {
        if (threadIdx.x < st) red[threadIdx.x] += red[threadIdx.x + st];
        __syncthreads();
    }
    if (threadIdx.x == 0) partials[blockIdx.x] = red[0];
}

extern "C" void kernel_launch(void* const* d_in, const int* in_sizes, int n_in,
                              void* d_out, int out_size, void* d_ws, size_t ws_size,
                              hipStream_t stream) {
    const float* f = (const float*)d_in[0];
    const float* m = (const float*)d_in[1];
    float* out = (float*)d_out;

    if (ws_size >= 4096) {
        float* partials = (float*)d_ws;
        lcc_fused<<<dim3(NXB, NYB), NT, 0, stream>>>(f, m, partials);
        lcc_finalize<<<1, 256, 0, stream>>>(partials, NXB * NYB, out);
    } else {
        const int nb = 512;
        float* partials = (float*)d_ws;
        lcc_direct<<<nb, 256, 0, stream>>>(f, m, partials);
        lcc_finalize<<<1, 256, 0, stream>>>(partials, nb, out);
    }
}